// Round 5
// baseline (318.815 us; speedup 1.0000x reference)
//
#include <hip/hip_runtime.h>

#define DEVFN __device__ __forceinline__

typedef __attribute__((ext_vector_type(8))) short short8;
typedef __attribute__((ext_vector_type(4))) float floatx4;
typedef unsigned short u16;
typedef unsigned int u32;

constexpr int B_   = 2;
constexpr int CIN  = 16;
constexpr int COUT = 16;
constexpr int T_   = 31;
constexpr int H_   = 128;
constexpr int W_   = 128;
constexpr int OC   = 6 * COUT;   // 96
constexpr int HW   = H_ * W_;    // 16384
constexpr int KVOL = CIN * 27;   // 432
constexpr int KP   = 448;        // K padded to 14 * 32

// padded x layout [b][TP][HP][WP][16ci], fp16
constexpr int TP = T_ + 2;       // 33
constexpr int HP = H_ + 2;       // 130
constexpr int WP = W_ + 2;       // 130
constexpr int Sh = WP * 16;
constexpr int St = HP * Sh;
constexpr int NPAD = B_ * TP * HP * WP;  // 1,115,400

// A-in-LDS: one phase = 7 k-steps, layout [sl(7)][m(6)][quad(4)][n(16)][j(8)]
constexpr int APH = 7 * 6 * 4 * 16 * 8;  // 21504 elems (43008 B)
// epilogue transpose chunk: 48 rows x 520 (512 + 8 pad) elems
constexpr int TSTRIDE = 520;
constexpr int SMEMN = 48 * TSTRIDE;      // 24960 elems (49920 B) >= APH

DEVFN float sigmoid_(float v) { return 1.f / (1.f + __expf(-v)); }
DEVFN float tanh_(float v)    { return 1.f - 2.f / (__expf(2.f * v) + 1.f); }

DEVFN u16 f2h(float v) {
  _Float16 h = (_Float16)v;
  u16 u; __builtin_memcpy(&u, &h, 2); return u;
}
DEVFN float h2f(u16 u) {
  _Float16 h; __builtin_memcpy(&h, &u, 2); return (float)h;
}

// delta (elems) into padded-x for kernel offset off = kd*9+kh*3+kw;
// off==27 (K pad) clamps to 26 — A weights there are zero.
DEVFN constexpr int dOff(int off) {
  const int o = (off < 27) ? off : 26;
  return (o / 9) * St + ((o % 9) / 3) * Sh + (o % 3) * 16;
}

// ---------------------------------------------------------------------------
// Pre-kernel 1: fp32 x -> fp16, ci-innermost, zero-padded borders.
// ---------------------------------------------------------------------------
__global__ __launch_bounds__(256) void pad_x_f16(const float* __restrict__ x,
                                                 u16* __restrict__ xh) {
  const int idx = blockIdx.x * 256 + threadIdx.x;
  if (idx >= NPAD) return;
  int r = idx;
  const int ww = r % WP; r /= WP;
  const int hh = r % HP; r /= HP;
  const int tt = r % TP; const int b = r / TP;
  const bool in_ = (tt >= 1) & (tt <= T_) & (hh >= 1) & (hh <= H_) &
                   (ww >= 1) & (ww <= W_);
  const int ts = in_ ? tt - 1 : 0, hs = in_ ? hh - 1 : 0, ws = in_ ? ww - 1 : 0;
  const float* xp = x + ((size_t)b * CIN * T_ + ts) * HW + hs * W_ + ws;
  u32 ph[8];
#pragma unroll
  for (int ci = 0; ci < 16; ++ci) {
    const float v = in_ ? xp[ci * (T_ * HW)] : 0.f;
    const u16 hu = f2h(v);
    if (ci & 1) ph[ci >> 1] |= ((u32)hu) << 16;
    else        ph[ci >> 1] = hu;
  }
  uint4* dh = (uint4*)(xh + (size_t)idx * 16);
  dh[0] = make_uint4(ph[0], ph[1], ph[2], ph[3]);
  dh[1] = make_uint4(ph[4], ph[5], ph[6], ph[7]);
}

// ---------------------------------------------------------------------------
// Pre-kernel 2: weights [oc][ci][27] fp32 -> LDS-ready fp16
// [s(14)][m(6)][quad(4)][n(16)][j(8)], oc = m*16+n, k = s*32+quad*8+j.
// ---------------------------------------------------------------------------
__global__ __launch_bounds__(256) void reorder_w(const float* __restrict__ cw,
                                                 u16* __restrict__ wr) {
  const int idx = blockIdx.x * 256 + threadIdx.x;
  if (idx >= OC * KP) return;
  const int j    = idx & 7;
  const int n    = (idx >> 3) & 15;
  const int quad = (idx >> 7) & 3;
  const int m    = (idx >> 9) % 6;
  const int s    = idx / 3072;
  const int oc   = m * 16 + n;
  const int k    = s * 32 + quad * 8 + j;
  const int off  = k >> 4, ci = k & 15;
  const float v  = (off < 27) ? cw[oc * KVOL + ci * 27 + off] : 0.f;
  wr[idx] = f2h(v);
}

// ---------------------------------------------------------------------------
// One k-phase (7 steps); PH compile-time so dOff folds to immediates.
// ---------------------------------------------------------------------------
template <int PH>
DEVFN void kphase(const u16* __restrict__ xh, const u16* As, int pbase, int n,
                  int quad, int qhalf, floatx4 (&acc)[6][4]) {
#pragma unroll
  for (int sl = 0; sl < 7; ++sl) {
    const int s = PH * 7 + sl;
    const int d = qhalf ? dOff(2 * s + 1) : dOff(2 * s);
    short8 bh[4];
#pragma unroll
    for (int j = 0; j < 4; ++j)
      bh[j] = *(const short8*)(xh + pbase + j * 256 + d);
#pragma unroll
    for (int m = 0; m < 6; ++m) {
      const short8 a =
          *(const short8*)(As + (sl * 6 + m) * 512 + quad * 128 + n * 8);
#pragma unroll
      for (int j = 0; j < 4; ++j)
        acc[m][j] =
            __builtin_amdgcn_mfma_f32_16x16x32_f16(a, bh[j], acc[m][j], 0, 0, 0);
    }
  }
}

// ---------------------------------------------------------------------------
// Main conv: implicit GEMM. Block = 8 waves (512 thr) covering 4 h rows;
// wave = 64 positions. Gates stored as PRE-ACTIVATION (bias added) fp16;
// activation is applied in the scan (its VALU is idle). Epilogue goes
// through an LDS transpose so global stores are 16 B contiguous.
// ---------------------------------------------------------------------------
__global__ __launch_bounds__(512) void conv_mfma(
    const u16* __restrict__ xh, const u16* __restrict__ wr,
    const float* __restrict__ cb, u16* __restrict__ gates) {
  const int lane = threadIdx.x & 63, wv = threadIdx.x >> 6;
  const int n = lane & 15, quad = lane >> 4;
  const int qhalf = quad >> 1, cihalf = quad & 1;
  const int h = blockIdx.x * 4 + (wv >> 1);
  const int wbase = (wv & 1) * 64;
  const int bt = blockIdx.y;
  const int b = bt / T_, t = bt - b * T_;

  __shared__ u16 smem[SMEMN];  // A-stage (21504) / transpose (24960)

  const int pbase = (((b * TP + t) * HP + h) * WP + wbase + n) * 16 + cihalf * 8;

  floatx4 acc[6][4];
#pragma unroll
  for (int m = 0; m < 6; ++m)
#pragma unroll
    for (int j = 0; j < 4; ++j) acc[m][j] = (floatx4)(0.f);

  // phase 0: stage A[s=0..6], compute
  for (int i = threadIdx.x; i < APH / 8; i += 512)
    ((uint4*)smem)[i] = ((const uint4*)wr)[i];
  __syncthreads();
  kphase<0>(xh, smem, pbase, n, quad, qhalf, acc);

  // phase 1: restage A[s=7..13], compute
  __syncthreads();
  for (int i = threadIdx.x; i < APH / 8; i += 512)
    ((uint4*)smem)[i] = ((const uint4*)(wr + APH))[i];
  __syncthreads();
  kphase<1>(xh, smem, pbase, n, quad, qhalf, acc);

  // epilogue: bias + LDS transpose + wide stores, two 3-m-tile chunks
  const int hl = wv >> 1;        // 0..3
  const int wl = (wv & 1) * 64;  // + j*16 + n
#pragma unroll
  for (int p = 0; p < 2; ++p) {
    __syncthreads();
#pragma unroll
    for (int mm = 0; mm < 3; ++mm) {
      const int m = p * 3 + mm;
#pragma unroll
      for (int r = 0; r < 4; ++r) {
        const int row = mm * 16 + quad * 4 + r;
        const float bias = cb[m * 16 + quad * 4 + r];
#pragma unroll
        for (int j = 0; j < 4; ++j)
          smem[row * TSTRIDE + hl * 128 + wl + j * 16 + n] =
              f2h(acc[m][j][r] + bias);
      }
    }
    __syncthreads();
#pragma unroll
    for (int it = 0; it < 6; ++it) {
      const int u = it * 512 + threadIdx.x;  // 0..3071
      const int row = u >> 6, col = u & 63;
      const short8 v = *(const short8*)(smem + row * TSTRIDE + col * 8);
      const int m = p * 3 + (row >> 4), c = row & 15;
      const int hh = blockIdx.x * 4 + (col >> 4);
      const int ww = (col & 15) * 8;
      *(short8*)(gates +
                 ((((m * B_ + b) * COUT + c) * T_ + t) * HW + hh * W_ + ww)) = v;
    }
  }
}

// ---------------------------------------------------------------------------
// Bidirectional SRU scan on RAW (pre-activation) fp16 gates. Activations
// applied here (memory-bound kernel, idle VALU). Per-thread t-arrays live
// in an LDS stash (fp16) instead of 93 VGPRs.
// ---------------------------------------------------------------------------
__global__ __launch_bounds__(256) void sru_scan_kernel(
    const u16* __restrict__ g, float* __restrict__ out) {
  const int tid  = threadIdx.x;
  const int idx  = blockIdx.x * 256 + tid;
  const int sp   = idx & (HW - 1);
  const int bc   = idx >> 14;
  const int base = bc * (T_ * HW) + sp;
  const int P    = B_ * COUT * T_ * HW;

  const u16* gWx = g + 0 * P + base;
  const u16* gF  = g + 1 * P + base;
  const u16* gF2 = g + 2 * P + base;
  const u16* gR  = g + 3 * P + base;
  const u16* gR2 = g + 4 * P + base;
  const u16* gX  = g + 5 * P + base;

  __shared__ u16 st[3 * T_ * 256];  // 47616 B: wx / x / htl per (t, thread)

  float C = 0.f;
#pragma unroll
  for (int t = 0; t < T_; ++t) {
    const float wx = tanh_(h2f(gWx[t * HW]));
    const float f  = sigmoid_(h2f(gF[t * HW]));
    const float r  = sigmoid_(h2f(gR[t * HW]));
    const float xv = tanh_(h2f(gX[t * HW]));
    C = (t == 0) ? (1.f - f) : (f * C + (1.f - f) * wx);
    const float htl = r * C + (1.f - r) * xv;
    st[(0 * T_ + t) * 256 + tid] = f2h(wx);
    st[(1 * T_ + t) * 256 + tid] = f2h(xv);
    st[(2 * T_ + t) * 256 + tid] = f2h(htl);
  }
  float C2 = 0.f;
#pragma unroll
  for (int t = T_ - 1; t >= 0; --t) {
    const float f2 = sigmoid_(h2f(gF2[t * HW]));
    const float r2 = sigmoid_(h2f(gR2[t * HW]));
    const float wx = h2f(st[(0 * T_ + t) * 256 + tid]);
    const float xv = h2f(st[(1 * T_ + t) * 256 + tid]);
    const float htl = h2f(st[(2 * T_ + t) * 256 + tid]);
    C2 = (t == T_ - 1) ? (1.f - f2) : (f2 * C2 + (1.f - f2) * wx);
    const float htr = r2 * C2 + (1.f - r2) * xv;
    out[base + t * HW] = htl + htr;
  }
}

// ---------------------------------------------------------------------------
// Fallback direct conv (ws too small). Stores pre-activation gates to match
// the scan's contract.
// ---------------------------------------------------------------------------
__global__ __launch_bounds__(256) void conv_gates_kernel(
    const float* __restrict__ x, const float* __restrict__ cw,
    const float* __restrict__ cb, u16* __restrict__ gates) {
  const int sp = blockIdx.x * 256 + threadIdx.x;
  const int oc = blockIdx.y;
  const int bt = blockIdx.z;
  const int b  = bt / T_;
  const int t  = bt - b * T_;
  const int h  = sp >> 7;
  const int wc = sp & (W_ - 1);

  __shared__ float wsh[KVOL];
  for (int i = threadIdx.x; i < KVOL; i += 256) wsh[i] = cw[oc * KVOL + i];
  __syncthreads();

  float acc = cb[oc];
  const float* xb = x + b * (CIN * T_ * HW);
  for (int ci = 0; ci < CIN; ++ci) {
    const float* xc = xb + ci * (T_ * HW);
#pragma unroll
    for (int kd = 0; kd < 3; ++kd) {
      const int tt = t + kd - 1;
      if ((unsigned)tt >= (unsigned)T_) continue;
      const float* xt = xc + tt * HW;
#pragma unroll
      for (int kh = 0; kh < 3; ++kh) {
        const int hh = h + kh - 1;
        if ((unsigned)hh >= (unsigned)H_) continue;
        const float* xr = xt + hh * W_;
        const float* wrp = &wsh[(ci * 3 + kd) * 9 + kh * 3];
        if (wc > 0)      acc += wrp[0] * xr[wc - 1];
        acc += wrp[1] * xr[wc];
        if (wc < W_ - 1) acc += wrp[2] * xr[wc + 1];
      }
    }
  }
  const int g = oc >> 4, c = oc & 15;
  const int off = (((g * B_ + b) * COUT + c) * T_ + t) * HW + sp;
  gates[off] = f2h(acc);
}

extern "C" void kernel_launch(void* const* d_in, const int* in_sizes, int n_in,
                              void* d_out, int out_size, void* d_ws,
                              size_t ws_size, hipStream_t stream) {
  (void)in_sizes; (void)n_in; (void)out_size;
  const float* x  = (const float*)d_in[0];
  const float* cw = (const float*)d_in[1];
  const float* cb = (const float*)d_in[2];
  float* out = (float*)d_out;

  const size_t planeElems = (size_t)B_ * COUT * T_ * HW;   // 16,252,928
  const size_t szGatesH = 6 * planeElems * sizeof(u16);    // 195,035,136
  const size_t szX      = (size_t)NPAD * 16 * sizeof(u16); // 35,692,800
  const size_t szW      = (size_t)OC * KP * sizeof(u16);   // 86,016

  const int splitBlocks = (NPAD + 255) / 256;
  const int wBlocks     = (OC * KP + 255) / 256;
  const dim3 gconv(H_ / 4, B_ * T_);              // 32 x 62, 512-thr blocks
  const int scanBlocks = (B_ * COUT * HW) / 256;  // 2048

  char* p = (char*)d_ws;
  u16* gates = (u16*)p;
  if (ws_size >= szGatesH + szX + szW) {
    u16* xh  = (u16*)(p + szGatesH);
    u16* wrp = (u16*)(p + szGatesH + szX);
    pad_x_f16<<<splitBlocks, 256, 0, stream>>>(x, xh);
    reorder_w<<<wBlocks, 256, 0, stream>>>(cw, wrp);
    conv_mfma<<<gconv, 512, 0, stream>>>(xh, wrp, cb, gates);
  } else {
    const dim3 gdir(HW / 256, OC, B_ * T_);
    conv_gates_kernel<<<gdir, 256, 0, stream>>>(x, cw, cb, gates);
  }
  sru_scan_kernel<<<scanBlocks, 256, 0, stream>>>(gates, out);
}